// Round 1
// baseline (424.519 us; speedup 1.0000x reference)
//
#include <hip/hip_runtime.h>

// LocalEnergy: fused geometry + 3-layer MLP energy sums, bf16 MFMA.
// B=128, L=2048, E=16, H=128. Out = 128 f32 (E_l+E_t+E_p per batch).

typedef short bf16x8 __attribute__((ext_vector_type(8)));
typedef float f32x4  __attribute__((ext_vector_type(4)));

constexpr int Bc = 128, Lc = 2048, Hc = 128;

__device__ __forceinline__ unsigned short f2bf(float f) {
    union { float f; unsigned u; } v; v.f = f;
    unsigned u = v.u;
    u = u + 0x7FFFu + ((u >> 16) & 1u);   // RTNE
    return (unsigned short)(u >> 16);
}

template<int TYPE> struct Cfg;
template<> struct Cfg<0> { static constexpr int GEOM=1, NEMB=2, DIN=33, K=64, ROWSB=Lc-1; };
template<> struct Cfg<1> { static constexpr int GEOM=1, NEMB=3, DIN=49, K=64, ROWSB=Lc-2; };
template<> struct Cfg<2> { static constexpr int GEOM=2, NEMB=4, DIN=66, K=96, ROWSB=Lc-3; };

__global__ void zero_out_kernel(float* out) { out[threadIdx.x] = 0.0f; }

template<int TYPE>
__global__ __launch_bounds__(256)
void energy_kernel(const float* __restrict__ R, const int* __restrict__ seq,
                   const float* __restrict__ emb,
                   const float* __restrict__ W1, const float* __restrict__ b1,
                   const float* __restrict__ W2, const float* __restrict__ b2,
                   const float* __restrict__ W3, const float* __restrict__ b3,
                   float* __restrict__ out)
{
    constexpr int GEOM = Cfg<TYPE>::GEOM, NEMB = Cfg<TYPE>::NEMB;
    constexpr int DIN  = Cfg<TYPE>::DIN,  K    = Cfg<TYPE>::K;
    constexpr int ROWSB = Cfg<TYPE>::ROWSB;
    constexpr int SA = K + 8;      // bf16 stride: Xs / W1t (16B-aligned rows, balanced banks)
    constexpr int SH = 128 + 8;    // bf16 stride: H1s / W2t
    constexpr int KS1 = K / 32;

    constexpr int XW_BYTES = 128 * SA * 2 * 2;            // Xs + W1t (phase 1)
    constexpr int H1_BYTES = 128 * SH * 2;                // H1s (phase 2, aliases Xs+W1t)
    constexpr int REGA = (XW_BYTES > H1_BYTES) ? XW_BYTES : H1_BYTES;
    constexpr int OFF_W2T  = REGA;
    constexpr int OFF_RBUF = OFF_W2T + 128 * SH * 2;
    constexpr int OFF_GEOM = OFF_RBUF + 132 * 3 * 4;
    constexpr int OFF_SEQ  = OFF_GEOM + 128 * 2 * 4;
    constexpr int OFF_EBUF = OFF_SEQ  + 132 * 4;
    constexpr int OFF_B1   = OFF_EBUF + 320 * 2;
    constexpr int OFF_B2   = OFF_B1 + 128 * 4;
    constexpr int OFF_W3   = OFF_B2 + 128 * 4;
    constexpr int OFF_PART = OFF_W3 + 128 * 4;
    constexpr int SMEM_SZ  = OFF_PART + 16;

    __shared__ __align__(16) char smem[SMEM_SZ];
    unsigned short* Xs   = (unsigned short*)(smem);
    unsigned short* W1t  = (unsigned short*)(smem + 128 * SA * 2);
    unsigned short* H1s  = (unsigned short*)(smem);             // aliases Xs/W1t
    unsigned short* W2t  = (unsigned short*)(smem + OFF_W2T);
    float*          Rbuf = (float*)(smem + OFF_RBUF);
    float*          geomb= (float*)(smem + OFF_GEOM);
    int*            seqb = (int*)(smem + OFF_SEQ);
    unsigned short* ebuf = (unsigned short*)(smem + OFF_EBUF);
    float*          b1s  = (float*)(smem + OFF_B1);
    float*          b2s  = (float*)(smem + OFF_B2);
    float*          w3s  = (float*)(smem + OFF_W3);
    float*          part = (float*)(smem + OFF_PART);

    const int tid = threadIdx.x;
    const int b   = blockIdx.y;
    const int i0  = blockIdx.x * 128;

    // ---- Phase A: stage R rows, seq, emb, biases ----
    for (int t = tid; t < 131 * 3; t += 256) {
        int row = i0 + t / 3;
        row = min(row, Lc - 1);
        Rbuf[t] = R[((size_t)b * Lc + row) * 3 + (t % 3)];
    }
    for (int t = tid; t < 131; t += 256)
        seqb[t] = seq[b * Lc + min(i0 + t, Lc - 1)];
    for (int t = tid; t < 320; t += 256)
        ebuf[t] = f2bf(emb[t]);
    for (int t = tid; t < 128; t += 256) {
        b1s[t] = b1[t]; b2s[t] = b2[t]; w3s[t] = W3[t];
    }
    __syncthreads();

    // ---- Phase B: geometry (threads 0..127) + weight staging (all) ----
    if (tid < 128) {
        const float* p0 = &Rbuf[tid * 3];
        float ax = p0[3] - p0[0], ay = p0[4] - p0[1], az = p0[5] - p0[2]; // d[r]
        float g0 = 0.f, g1 = 0.f;
        if (TYPE == 0) {
            g0 = sqrtf(ax * ax + ay * ay + az * az);
        } else if (TYPE == 1) {
            float bx = p0[6] - p0[3], by = p0[7] - p0[4], bz = p0[8] - p0[5]; // d[r+1]
            float duv = -(ax * bx + ay * by + az * bz);
            float na2 = ax * ax + ay * ay + az * az;
            float nb2 = bx * bx + by * by + bz * bz;
            float cosv = duv / sqrtf(na2 * nb2);
            g0 = fminf(fmaxf(cosv, -1.0f), 1.0f);
        } else {
            float bx = p0[6] - p0[3], by = p0[7] - p0[4], bz = p0[8] - p0[5];   // d[r+1]
            float cx = p0[9] - p0[6], cy = p0[10] - p0[7], cz = p0[11] - p0[8]; // d[r+2]
            float n1x = ay * bz - az * by, n1y = az * bx - ax * bz, n1z = ax * by - ay * bx;
            float n2x = by * cz - bz * cy, n2y = bz * cx - bx * cz, n2z = bx * cy - by * cx;
            float binv = 1.0f / sqrtf(bx * bx + by * by + bz * bz);
            float ux = bx * binv, uy = by * binv, uz = bz * binv;
            float m1x = n1y * uz - n1z * uy, m1y = n1z * ux - n1x * uz, m1z = n1x * uy - n1y * ux;
            float yv = m1x * n2x + m1y * n2y + m1z * n2z;
            float xv = n1x * n2x + n1y * n2y + n1z * n2z;
            float inv = 1.0f / sqrtf(xv * xv + yv * yv);
            g0 = yv * inv;  // sin(phi)
            g1 = xv * inv;  // cos(phi)
        }
        geomb[tid * 2]     = g0;
        geomb[tid * 2 + 1] = g1;
    }
    // W1^T into LDS (n-major rows, k contiguous), bf16, zero-pad k>=DIN
    for (int idx = tid; idx < 128 * K; idx += 256) {
        int n = idx & 127, k = idx >> 7;
        float v = (k < DIN) ? W1[k * Hc + n] : 0.0f;
        W1t[n * SA + k] = f2bf(v);
    }
    // W2^T into LDS
    for (int idx = tid; idx < 128 * 128; idx += 256) {
        int n = idx & 127, k = idx >> 7;
        W2t[n * SH + k] = f2bf(W2[k * 128 + n]);
    }
    __syncthreads();

    // ---- Phase C: build feature rows Xs (bf16), zero-pad k>=DIN ----
    for (int idx = tid; idx < 128 * K; idx += 256) {
        int r = idx / K, k = idx - r * K;
        unsigned short v;
        if (k < GEOM) {
            v = f2bf(geomb[r * 2 + k]);
        } else if (k < GEOM + 16 * NEMB) {
            int j = (k - GEOM) >> 4, el = (k - GEOM) & 15;
            v = ebuf[seqb[r + j] * 16 + el];
        } else {
            v = 0;
        }
        Xs[r * SA + k] = v;
    }
    __syncthreads();

    // ---- GEMM1: H1 = relu(X @ W1 + b1) ----
    const int lane = tid & 63, wv = tid >> 6;
    const int q = lane >> 4, c = lane & 15;

    f32x4 acc[2][8];
#pragma unroll
    for (int i = 0; i < 2; ++i)
#pragma unroll
        for (int nt = 0; nt < 8; ++nt)
            acc[i][nt] = (f32x4){0.f, 0.f, 0.f, 0.f};

#pragma unroll
    for (int ks = 0; ks < KS1; ++ks) {
        bf16x8 a0 = *(const bf16x8*)&Xs[(wv * 32 +      c) * SA + ks * 32 + q * 8];
        bf16x8 a1 = *(const bf16x8*)&Xs[(wv * 32 + 16 + c) * SA + ks * 32 + q * 8];
#pragma unroll
        for (int nt = 0; nt < 8; ++nt) {
            bf16x8 bb = *(const bf16x8*)&W1t[(nt * 16 + c) * SA + ks * 32 + q * 8];
            acc[0][nt] = __builtin_amdgcn_mfma_f32_16x16x32_bf16(a0, bb, acc[0][nt], 0, 0, 0);
            acc[1][nt] = __builtin_amdgcn_mfma_f32_16x16x32_bf16(a1, bb, acc[1][nt], 0, 0, 0);
        }
    }
    __syncthreads();  // all reads of Xs/W1t done before overwriting with H1s

    // bias + relu -> H1s (bf16), C/D layout: row=(q*4+reg), col=lane&15 (+tile offsets)
#pragma unroll
    for (int i = 0; i < 2; ++i)
#pragma unroll
        for (int nt = 0; nt < 8; ++nt)
#pragma unroll
            for (int reg = 0; reg < 4; ++reg) {
                int m   = wv * 32 + i * 16 + q * 4 + reg;
                int col = nt * 16 + c;
                float v = acc[i][nt][reg] + b1s[col];
                H1s[m * SH + col] = f2bf(fmaxf(v, 0.0f));
            }
    __syncthreads();

    // ---- GEMM2: H2 = relu(H1 @ W2 + b2); fused dot with W3 in epilogue ----
#pragma unroll
    for (int i = 0; i < 2; ++i)
#pragma unroll
        for (int nt = 0; nt < 8; ++nt)
            acc[i][nt] = (f32x4){0.f, 0.f, 0.f, 0.f};

#pragma unroll
    for (int ks = 0; ks < 4; ++ks) {
        bf16x8 a0 = *(const bf16x8*)&H1s[(wv * 32 +      c) * SH + ks * 32 + q * 8];
        bf16x8 a1 = *(const bf16x8*)&H1s[(wv * 32 + 16 + c) * SH + ks * 32 + q * 8];
#pragma unroll
        for (int nt = 0; nt < 8; ++nt) {
            bf16x8 bb = *(const bf16x8*)&W2t[(nt * 16 + c) * SH + ks * 32 + q * 8];
            acc[0][nt] = __builtin_amdgcn_mfma_f32_16x16x32_bf16(a0, bb, acc[0][nt], 0, 0, 0);
            acc[1][nt] = __builtin_amdgcn_mfma_f32_16x16x32_bf16(a1, bb, acc[1][nt], 0, 0, 0);
        }
    }

    // epilogue: relu(h2 + b2) . W3, mask invalid rows, reduce
    float p = 0.0f;
#pragma unroll
    for (int i = 0; i < 2; ++i)
#pragma unroll
        for (int reg = 0; reg < 4; ++reg) {
            int m = wv * 32 + i * 16 + q * 4 + reg;
            if (i0 + m < ROWSB) {
                float s = 0.0f;
#pragma unroll
                for (int nt = 0; nt < 8; ++nt) {
                    int col = nt * 16 + c;
                    s += fmaxf(acc[i][nt][reg] + b2s[col], 0.0f) * w3s[col];
                }
                p += s;
            }
        }
#pragma unroll
    for (int off = 32; off > 0; off >>= 1)
        p += __shfl_down(p, off);
    if (lane == 0) part[wv] = p;
    __syncthreads();
    if (tid == 0) {
        int vc = min(ROWSB - i0, 128);
        float tot = part[0] + part[1] + part[2] + part[3] + b3[0] * (float)vc;
        atomicAdd(&out[b], tot);
    }
}

extern "C" void kernel_launch(void* const* d_in, const int* in_sizes, int n_in,
                              void* d_out, int out_size, void* d_ws, size_t ws_size,
                              hipStream_t stream) {
    const float* R   = (const float*)d_in[0];
    const int*   seq = (const int*)d_in[1];
    const float* emb = (const float*)d_in[2];
    float* out = (float*)d_out;

    zero_out_kernel<<<dim3(1), dim3(128), 0, stream>>>(out);

    dim3 grid(16, Bc), block(256);
    energy_kernel<0><<<grid, block, 0, stream>>>(
        R, seq, emb,
        (const float*)d_in[3], (const float*)d_in[4], (const float*)d_in[5],
        (const float*)d_in[6], (const float*)d_in[7], (const float*)d_in[8], out);
    energy_kernel<1><<<grid, block, 0, stream>>>(
        R, seq, emb,
        (const float*)d_in[9], (const float*)d_in[10], (const float*)d_in[11],
        (const float*)d_in[12], (const float*)d_in[13], (const float*)d_in[14], out);
    energy_kernel<2><<<grid, block, 0, stream>>>(
        R, seq, emb,
        (const float*)d_in[15], (const float*)d_in[16], (const float*)d_in[17],
        (const float*)d_in[18], (const float*)d_in[19], (const float*)d_in[20], out);
}

// Round 2
// 234.216 us; speedup vs baseline: 1.8125x; 1.8125x over previous
//
#include <hip/hip_runtime.h>

// LocalEnergy: fused geometry + 3-layer MLP energy sums, bf16 MFMA.
// B=128, L=2048, E=16, H=128. Out = 128 f32 (E_l+E_t+E_p per batch).
//
// R2: weights pre-converted to bf16 LDS-layout in d_ws by prep_kernel (once
// per launch); geometry features folded into per-row bias (K = NEMB*16);
// vectorized staging + feature build; LDS <= 78KB -> 2 blocks/CU.

typedef short bf16x8 __attribute__((ext_vector_type(8)));
typedef float f32x4  __attribute__((ext_vector_type(4)));

constexpr int Bc = 128, Lc = 2048, Hc = 128;
constexpr int SH = 136;            // H1s / W2t row stride (bf16): 16B-aligned, 2-way banks (free)

__device__ __forceinline__ unsigned short f2bf(float f) {
    union { float f; unsigned u; } v; v.f = f;
    unsigned u = v.u;
    u = u + 0x7FFFu + ((u >> 16) & 1u);   // RTNE
    return (unsigned short)(u >> 16);
}

template<int TYPE> struct Cfg;
template<> struct Cfg<0> { static constexpr int NG=1, NEMB=2, K=32, ROWSB=Lc-1; };
template<> struct Cfg<1> { static constexpr int NG=1, NEMB=3, K=64, ROWSB=Lc-2; };
template<> struct Cfg<2> { static constexpr int NG=2, NEMB=4, K=64, ROWSB=Lc-3; };

// workspace layout (bytes)
__device__ constexpr int SA_T[3]     = {40, 72, 72};                    // K+8
__device__ constexpr int WS_W1T[3]   = {0, 10240, 28672};               // 128*SA*2 each
__device__ constexpr int WS_W2T[3]   = {47104, 47104 + 34816, 47104 + 2*34816}; // 128*136*2
__device__ constexpr int WS_EB       = 151552;                          // 320 bf16
__device__ constexpr int WS_W1G[3]   = {152192, 152192 + 512, 152192 + 1024};   // NG*128 f32

__global__ void zero_out_kernel(float* out) { out[threadIdx.x] = 0.0f; }

__global__ __launch_bounds__(256)
void prep_kernel(const float* __restrict__ W1_0, const float* __restrict__ W1_1,
                 const float* __restrict__ W1_2,
                 const float* __restrict__ W2_0, const float* __restrict__ W2_1,
                 const float* __restrict__ W2_2,
                 const float* __restrict__ emb, char* __restrict__ ws)
{
    const int tid = blockIdx.x * 256 + threadIdx.x;
    const int np  = gridDim.x * 256;
    const float* W1s[3] = {W1_0, W1_1, W1_2};
    const float* W2s[3] = {W2_0, W2_1, W2_2};
    const int NGs[3] = {1, 1, 2}, NEs[3] = {2, 3, 4};
#pragma unroll
    for (int t = 0; t < 3; ++t) {
        const int SA = SA_T[t], DINg = NEs[t] * 16, NG = NGs[t];
        unsigned short* w1t = (unsigned short*)(ws + WS_W1T[t]);
        for (int i = tid; i < 128 * SA; i += np) {
            int n = i / SA, k = i - n * SA;
            float v = (k < DINg) ? W1s[t][(k + NG) * Hc + n] : 0.0f;
            w1t[i] = f2bf(v);
        }
        unsigned short* w2t = (unsigned short*)(ws + WS_W2T[t]);
        for (int i = tid; i < 128 * SH; i += np) {
            int n = i / SH, k = i - n * SH;
            float v = (k < 128) ? W2s[t][k * Hc + n] : 0.0f;
            w2t[i] = f2bf(v);
        }
        float* w1g = (float*)(ws + WS_W1G[t]);
        for (int i = tid; i < NG * 128; i += np) w1g[i] = W1s[t][i];
    }
    unsigned short* eb = (unsigned short*)(ws + WS_EB);
    for (int i = tid; i < 320; i += np) eb[i] = f2bf(emb[i]);
}

template<int TYPE>
__global__ __launch_bounds__(256, 2)
void energy_kernel(const float* __restrict__ R, const int* __restrict__ seq,
                   const char* __restrict__ ws,
                   const float* __restrict__ b1, const float* __restrict__ b2,
                   const float* __restrict__ W3, const float* __restrict__ b3,
                   float* __restrict__ out)
{
    constexpr int NG = Cfg<TYPE>::NG, NEMB = Cfg<TYPE>::NEMB;
    constexpr int K  = Cfg<TYPE>::K,  ROWSB = Cfg<TYPE>::ROWSB;
    constexpr int SA = K + 8;
    constexpr int KS = K / 32;
    constexpr int JC = K / 8;                       // 16B chunks per feature row

    constexpr int XW   = 2 * 128 * SA * 2;          // Xs + W1t
    constexpr int H1B  = 128 * SH * 2;              // H1s (aliases Xs/W1t region)
    constexpr int REGA = (XW > H1B) ? XW : H1B;
    constexpr int O_W2T = REGA;
    constexpr int O_RB  = O_W2T + 128 * SH * 2;
    constexpr int O_GM  = O_RB + 132 * 3 * 4;
    constexpr int O_SQ  = O_GM + 2 * 128 * 4;
    constexpr int O_EB  = O_SQ + 132 * 4;
    constexpr int O_B1  = O_EB + 640;
    constexpr int O_B2  = O_B1 + 512;
    constexpr int O_W3  = O_B2 + 512;
    constexpr int O_WG  = O_W3 + 512;
    constexpr int O_PT  = O_WG + 2 * 512;
    constexpr int SZ    = O_PT + 16;

    __shared__ __align__(16) char smem[SZ];
    unsigned short* Xs   = (unsigned short*)(smem);
    unsigned short* W1t  = (unsigned short*)(smem + 128 * SA * 2);
    unsigned short* H1s  = (unsigned short*)(smem);            // aliases Xs/W1t
    unsigned short* W2t  = (unsigned short*)(smem + O_W2T);
    float*          Rbuf = (float*)(smem + O_RB);
    float*          geomb= (float*)(smem + O_GM);              // [2][128]
    int*            seqb = (int*)(smem + O_SQ);
    unsigned short* ebuf = (unsigned short*)(smem + O_EB);
    float*          b1s  = (float*)(smem + O_B1);
    float*          b2s  = (float*)(smem + O_B2);
    float*          w3s  = (float*)(smem + O_W3);
    float*          w1gs = (float*)(smem + O_WG);              // [NG][128]
    float*          part = (float*)(smem + O_PT);

    const int tid = threadIdx.x;
    const int b   = blockIdx.y;
    const int i0  = blockIdx.x * 128;

    // ---- Phase A: vectorized staging (pre-converted bf16 from ws) ----
    {
        const uint4* s1 = (const uint4*)(ws + WS_W1T[TYPE]);
        uint4*       d1 = (uint4*)W1t;
        for (int t = tid; t < 128 * SA * 2 / 16; t += 256) d1[t] = s1[t];
        const uint4* s2 = (const uint4*)(ws + WS_W2T[TYPE]);
        uint4*       d2 = (uint4*)W2t;
        for (int t = tid; t < 128 * SH * 2 / 16; t += 256) d2[t] = s2[t];
        const uint4* se = (const uint4*)(ws + WS_EB);
        for (int t = tid; t < 40; t += 256) ((uint4*)ebuf)[t] = se[t];
        const float* sg = (const float*)(ws + WS_W1G[TYPE]);
        for (int t = tid; t < NG * 128; t += 256) w1gs[t] = sg[t];
    }
    for (int t = tid; t < 131 * 3; t += 256) {
        int row = min(i0 + t / 3, Lc - 1);
        Rbuf[t] = R[((size_t)b * Lc + row) * 3 + (t % 3)];
    }
    for (int t = tid; t < 131; t += 256)
        seqb[t] = seq[b * Lc + min(i0 + t, Lc - 1)];
    for (int t = tid; t < 128; t += 256) {
        b1s[t] = b1[t]; b2s[t] = b2[t]; w3s[t] = W3[t];
    }
    __syncthreads();

    // ---- Phase B: geometry (threads 0..127) -> geomb; feature rows -> Xs ----
    if (tid < 128) {
        const float* p0 = &Rbuf[tid * 3];
        float ax = p0[3] - p0[0], ay = p0[4] - p0[1], az = p0[5] - p0[2]; // d[r]
        float g0 = 0.f, g1 = 0.f;
        if (TYPE == 0) {
            g0 = sqrtf(ax * ax + ay * ay + az * az);
        } else if (TYPE == 1) {
            float bx = p0[6] - p0[3], by = p0[7] - p0[4], bz = p0[8] - p0[5];
            float duv = -(ax * bx + ay * by + az * bz);
            float na2 = ax * ax + ay * ay + az * az;
            float nb2 = bx * bx + by * by + bz * bz;
            float cosv = duv / sqrtf(na2 * nb2);
            g0 = fminf(fmaxf(cosv, -1.0f), 1.0f);
        } else {
            float bx = p0[6] - p0[3], by = p0[7] - p0[4], bz = p0[8] - p0[5];
            float cx = p0[9] - p0[6], cy = p0[10] - p0[7], cz = p0[11] - p0[8];
            float n1x = ay * bz - az * by, n1y = az * bx - ax * bz, n1z = ax * by - ay * bx;
            float n2x = by * cz - bz * cy, n2y = bz * cx - bx * cz, n2z = bx * cy - by * cx;
            float binv = 1.0f / sqrtf(bx * bx + by * by + bz * bz);
            float ux = bx * binv, uy = by * binv, uz = bz * binv;
            float m1x = n1y * uz - n1z * uy, m1y = n1z * ux - n1x * uz, m1z = n1x * uy - n1y * ux;
            float yv = m1x * n2x + m1y * n2y + m1z * n2z;
            float xv = n1x * n2x + n1y * n2y + n1z * n2z;
            float inv = 1.0f / sqrtf(xv * xv + yv * yv);
            g0 = yv * inv;  // sin(phi)
            g1 = xv * inv;  // cos(phi)
        }
        geomb[tid] = g0;
        geomb[128 + tid] = g1;
    }
    // Xs rows = concatenated embedding rows (16B vector copies), zero-pad tail
    for (int idx = tid; idx < 128 * JC; idx += 256) {
        int r = idx / JC, jc = idx - r * JC;
        uint4 v = make_uint4(0u, 0u, 0u, 0u);
        if (jc < NEMB * 2) {
            int j = jc >> 1, h = jc & 1;
            v = *(const uint4*)&ebuf[seqb[r + j] * 16 + h * 8];
        }
        *(uint4*)&Xs[r * SA + jc * 8] = v;
    }
    __syncthreads();

    // ---- GEMM1: H1 = relu(Xe @ W1e + b1 + geom-fold) ----
    const int lane = tid & 63, wv = tid >> 6;
    const int q = lane >> 4, c = lane & 15;

    f32x4 acc[2][8];
#pragma unroll
    for (int i = 0; i < 2; ++i)
#pragma unroll
        for (int nt = 0; nt < 8; ++nt)
            acc[i][nt] = (f32x4){0.f, 0.f, 0.f, 0.f};

#pragma unroll
    for (int ks = 0; ks < KS; ++ks) {
        bf16x8 a0 = *(const bf16x8*)&Xs[(wv * 32 +      c) * SA + ks * 32 + q * 8];
        bf16x8 a1 = *(const bf16x8*)&Xs[(wv * 32 + 16 + c) * SA + ks * 32 + q * 8];
#pragma unroll
        for (int nt = 0; nt < 8; ++nt) {
            bf16x8 bb = *(const bf16x8*)&W1t[(nt * 16 + c) * SA + ks * 32 + q * 8];
            acc[0][nt] = __builtin_amdgcn_mfma_f32_16x16x32_bf16(a0, bb, acc[0][nt], 0, 0, 0);
            acc[1][nt] = __builtin_amdgcn_mfma_f32_16x16x32_bf16(a1, bb, acc[1][nt], 0, 0, 0);
        }
    }
    __syncthreads();  // Xs/W1t reads done before H1s overwrite

    // bias + geometry fold + relu -> H1s (C/D layout: row=q*4+reg, col=lane&15)
#pragma unroll
    for (int i = 0; i < 2; ++i)
#pragma unroll
        for (int nt = 0; nt < 8; ++nt)
#pragma unroll
            for (int reg = 0; reg < 4; ++reg) {
                int m   = wv * 32 + i * 16 + q * 4 + reg;
                int col = nt * 16 + c;
                float v = acc[i][nt][reg] + b1s[col] + geomb[m] * w1gs[col];
                if (NG == 2) v += geomb[128 + m] * w1gs[128 + col];
                H1s[m * SH + col] = f2bf(fmaxf(v, 0.0f));
            }
    __syncthreads();

    // ---- GEMM2: relu(H1 @ W2 + b2) . W3, fused epilogue ----
#pragma unroll
    for (int i = 0; i < 2; ++i)
#pragma unroll
        for (int nt = 0; nt < 8; ++nt)
            acc[i][nt] = (f32x4){0.f, 0.f, 0.f, 0.f};

#pragma unroll
    for (int ks = 0; ks < 4; ++ks) {
        bf16x8 a0 = *(const bf16x8*)&H1s[(wv * 32 +      c) * SH + ks * 32 + q * 8];
        bf16x8 a1 = *(const bf16x8*)&H1s[(wv * 32 + 16 + c) * SH + ks * 32 + q * 8];
#pragma unroll
        for (int nt = 0; nt < 8; ++nt) {
            bf16x8 bb = *(const bf16x8*)&W2t[(nt * 16 + c) * SH + ks * 32 + q * 8];
            acc[0][nt] = __builtin_amdgcn_mfma_f32_16x16x32_bf16(a0, bb, acc[0][nt], 0, 0, 0);
            acc[1][nt] = __builtin_amdgcn_mfma_f32_16x16x32_bf16(a1, bb, acc[1][nt], 0, 0, 0);
        }
    }

    float p = 0.0f;
#pragma unroll
    for (int i = 0; i < 2; ++i)
#pragma unroll
        for (int reg = 0; reg < 4; ++reg) {
            int m = wv * 32 + i * 16 + q * 4 + reg;
            if (i0 + m < ROWSB) {
                float s = 0.0f;
#pragma unroll
                for (int nt = 0; nt < 8; ++nt) {
                    int col = nt * 16 + c;
                    s += fmaxf(acc[i][nt][reg] + b2s[col], 0.0f) * w3s[col];
                }
                p += s;
            }
        }
#pragma unroll
    for (int off = 32; off > 0; off >>= 1)
        p += __shfl_down(p, off);
    if (lane == 0) part[wv] = p;
    __syncthreads();
    if (tid == 0) {
        int vc = min(ROWSB - i0, 128);
        float tot = part[0] + part[1] + part[2] + part[3] + b3[0] * (float)vc;
        atomicAdd(&out[b], tot);
    }
}

extern "C" void kernel_launch(void* const* d_in, const int* in_sizes, int n_in,
                              void* d_out, int out_size, void* d_ws, size_t ws_size,
                              hipStream_t stream) {
    const float* R   = (const float*)d_in[0];
    const int*   seq = (const int*)d_in[1];
    const float* emb = (const float*)d_in[2];
    float* out = (float*)d_out;
    char*  ws  = (char*)d_ws;

    prep_kernel<<<dim3(64), dim3(256), 0, stream>>>(
        (const float*)d_in[3], (const float*)d_in[9], (const float*)d_in[15],
        (const float*)d_in[5], (const float*)d_in[11], (const float*)d_in[17],
        emb, ws);
    zero_out_kernel<<<dim3(1), dim3(128), 0, stream>>>(out);

    dim3 grid(16, Bc), block(256);
    energy_kernel<0><<<grid, block, 0, stream>>>(
        R, seq, ws, (const float*)d_in[4], (const float*)d_in[6],
        (const float*)d_in[7], (const float*)d_in[8], out);
    energy_kernel<1><<<grid, block, 0, stream>>>(
        R, seq, ws, (const float*)d_in[10], (const float*)d_in[12],
        (const float*)d_in[13], (const float*)d_in[14], out);
    energy_kernel<2><<<grid, block, 0, stream>>>(
        R, seq, ws, (const float*)d_in[16], (const float*)d_in[18],
        (const float*)d_in[19], (const float*)d_in[20], out);
}

// Round 3
// 186.398 us; speedup vs baseline: 2.2775x; 1.2565x over previous
//
#include <hip/hip_runtime.h>

// LocalEnergy R3: single fused kernel, weights in registers, no LDS weight
// staging. B=128, L=2048, E=16, H=128. Out = 128 f32.
//
// GEMM1 operand-swapped: D[hid][row] = W1t(A) @ X^T(B); B-frags gathered
// directly from embedding table in LDS; geometry + b1 folded into K-slots
// (types 0/1) or epilogue registers (type 2). GEMM2: D[row][col2] with W2
// B-frags persistent in VGPRs (waves partition col2; W3-dot is a reduction
// over col2 so partials just add).

typedef short bf16x8 __attribute__((ext_vector_type(8)));
typedef float f32x4  __attribute__((ext_vector_type(4)));

constexpr int Lc = 2048;

union FragU { uint4 u; bf16x8 v; unsigned short s[8]; };

__device__ __forceinline__ unsigned short f2bf(float f) {
    union { float f; unsigned u; } v; v.f = f;
    unsigned u = v.u;
    u = u + 0x7FFFu + ((u >> 16) & 1u);   // RTNE
    return (unsigned short)(u >> 16);
}

// pack two f32 -> two bf16 (round-half-up) in one v_perm
__device__ __forceinline__ unsigned pkbf(float a, float b) {
    unsigned ua = __float_as_uint(a) + 0x8000u;
    unsigned ub = __float_as_uint(b) + 0x8000u;
    return __builtin_amdgcn_perm(ub, ua, 0x07060302u);  // [a.hi16, b.hi16]
}

// ws layout (bytes):
//   W2T[t] @ t*32768          : [col2=128][k=128] bf16, k-contig
//   W1T[t] @ 98304 + t*16384  : [hid=128][k=64]  bf16, k-contig
//     t0: k<32 emb (W1 rows 1+k), k=32 geom row0, k=33 b1;  t1: same at 48/49
//     t2: k<64 emb (W1 rows 2+k); geom/b1 handled in epilogue
__global__ __launch_bounds__(256)
void prep_kernel(const float* __restrict__ W1_0, const float* __restrict__ b1_0,
                 const float* __restrict__ W1_1, const float* __restrict__ b1_1,
                 const float* __restrict__ W1_2,
                 const float* __restrict__ W2_0, const float* __restrict__ W2_1,
                 const float* __restrict__ W2_2,
                 char* __restrict__ ws, float* __restrict__ out)
{
    const int tid = blockIdx.x * 256 + threadIdx.x;
    const int np  = gridDim.x * 256;
    if (blockIdx.x == 0 && threadIdx.x < 128) out[threadIdx.x] = 0.0f;

    unsigned short* d2 = (unsigned short*)ws;
    for (int i = tid; i < 3 * 16384; i += np) {
        int t = i >> 14, r = i & 16383, col = r >> 7, k = r & 127;
        const float* W2 = (t == 0) ? W2_0 : (t == 1) ? W2_1 : W2_2;
        d2[i] = f2bf(W2[k * 128 + col]);
    }
    unsigned short* d1 = (unsigned short*)(ws + 98304);
    for (int i = tid; i < 3 * 8192; i += np) {
        int t = i >> 13, r = i & 8191, hid = r >> 6, k = r & 63;
        float v = 0.0f;
        if (t == 0) {
            if (k < 32) v = W1_0[(1 + k) * 128 + hid];
            else if (k == 32) v = W1_0[hid];
            else if (k == 33) v = b1_0[hid];
        } else if (t == 1) {
            if (k < 48) v = W1_1[(1 + k) * 128 + hid];
            else if (k == 48) v = W1_1[hid];
            else if (k == 49) v = b1_1[hid];
        } else {
            v = W1_2[(2 + k) * 128 + hid];
        }
        d1[i] = f2bf(v);
    }
}

template<int TYPE>
__device__ __forceinline__ void body(
    const float* __restrict__ R, const int* __restrict__ seq,
    const float* __restrict__ emb, const char* __restrict__ ws,
    const float* __restrict__ W1g, const float* __restrict__ b1g,
    const float* __restrict__ b2, const float* __restrict__ w3,
    const float* __restrict__ b3, float* __restrict__ out)
{
    constexpr int NEMB  = (TYPE == 0) ? 2 : (TYPE == 1) ? 3 : 4;
    constexpr int SB    = NEMB * 16;
    constexpr int ROWSB = Lc - 1 - TYPE;
    constexpr int SHs   = 136;

    extern __shared__ char smem[];
    unsigned short* H1s  = (unsigned short*)smem;            // 128*136*2 = 34816
    float*          Rbuf = (float*)(smem + 34816);           // 393 f32
    float*          geomb= (float*)(smem + 36416);           // [2][128] f32
    int*            seqb = (int*)(smem + 37440);             // 131 i32
    unsigned short* ebuf = (unsigned short*)(smem + 37984);  // 320 bf16
    float*          part = (float*)(smem + 38624);           // 4 f32

    const int tid = threadIdx.x;
    const int b   = blockIdx.y;
    const int i0  = blockIdx.x * 128;
    const int lane = tid & 63, wv = tid >> 6;
    const int q = lane >> 4, c = lane & 15;

    const unsigned short* w1t = (const unsigned short*)(ws + 98304 + TYPE * 16384);
    const unsigned short* w2t = (const unsigned short*)(ws + TYPE * 32768);

    // ---- persistent weight fragments (global -> VGPR, L2-hot) ----
    FragU A1[2][2], B2[2][4];
#pragma unroll
    for (int mt = 0; mt < 2; ++mt)
#pragma unroll
        for (int ks = 0; ks < 2; ++ks)
            A1[mt][ks].u = *(const uint4*)&w1t[(wv * 32 + mt * 16 + c) * 64 + ks * 32 + q * 8];
#pragma unroll
    for (int nt = 0; nt < 2; ++nt)
#pragma unroll
        for (int ks = 0; ks < 4; ++ks)
            B2[nt][ks].u = *(const uint4*)&w2t[(wv * 32 + nt * 16 + c) * 128 + ks * 32 + q * 8];
    float b2v[2], w3v[2];
#pragma unroll
    for (int nt = 0; nt < 2; ++nt) {
        int col2 = wv * 32 + nt * 16 + c;
        b2v[nt] = b2[col2]; w3v[nt] = w3[col2];
    }
    float b1v[8], g0v[8], g1v[8];
    if (TYPE == 2) {
#pragma unroll
        for (int mt = 0; mt < 2; ++mt)
#pragma unroll
            for (int rg = 0; rg < 4; ++rg) {
                int hid = wv * 32 + mt * 16 + q * 4 + rg;
                b1v[mt * 4 + rg] = b1g[hid];
                g0v[mt * 4 + rg] = W1g[hid];
                g1v[mt * 4 + rg] = W1g[128 + hid];
            }
    }

    // ---- stage R / seq / emb ----
    for (int t = tid; t < 393; t += 256) {
        int lr = t / 3, comp = t - lr * 3;
        int row = min(i0 + lr, Lc - 1);
        Rbuf[t] = R[((size_t)b * Lc + row) * 3 + comp];
    }
    for (int t = tid; t < 131; t += 256)
        seqb[t] = seq[b * Lc + min(i0 + t, Lc - 1)];
    for (int t = tid; t < 320; t += 256)
        ebuf[t] = f2bf(emb[t]);
    __syncthreads();

    // ---- geometry -> geomb ----
    if (tid < 128) {
        const float* p0 = &Rbuf[tid * 3];
        float ax = p0[3] - p0[0], ay = p0[4] - p0[1], az = p0[5] - p0[2];
        float g0 = 0.f, g1 = 0.f;
        if (TYPE == 0) {
            g0 = sqrtf(ax * ax + ay * ay + az * az);
        } else if (TYPE == 1) {
            float bx = p0[6] - p0[3], by = p0[7] - p0[4], bz = p0[8] - p0[5];
            float duv = -(ax * bx + ay * by + az * bz);
            float na2 = ax * ax + ay * ay + az * az;
            float nb2 = bx * bx + by * by + bz * bz;
            float cosv = duv / sqrtf(na2 * nb2);
            g0 = fminf(fmaxf(cosv, -1.0f), 1.0f);
        } else {
            float bx = p0[6] - p0[3], by = p0[7] - p0[4], bz = p0[8] - p0[5];
            float cx = p0[9] - p0[6], cy = p0[10] - p0[7], cz = p0[11] - p0[8];
            float n1x = ay * bz - az * by, n1y = az * bx - ax * bz, n1z = ax * by - ay * bx;
            float n2x = by * cz - bz * cy, n2y = bz * cx - bx * cz, n2z = bx * cy - by * cx;
            float binv = 1.0f / sqrtf(bx * bx + by * by + bz * bz);
            float ux = bx * binv, uy = by * binv, uz = bz * binv;
            float m1x = n1y * uz - n1z * uy, m1y = n1z * ux - n1x * uz, m1z = n1x * uy - n1y * ux;
            float yv = m1x * n2x + m1y * n2y + m1z * n2z;
            float xv = n1x * n2x + n1y * n2y + n1z * n2z;
            float inv = 1.0f / sqrtf(xv * xv + yv * yv);
            g0 = yv * inv; g1 = xv * inv;
        }
        geomb[tid] = g0;
        geomb[128 + tid] = g1;
    }
    __syncthreads();

    // ---- GEMM1 (swapped): acc1[mt][nt] = D[hid][row] ----
    f32x4 acc1[2][8];
#pragma unroll
    for (int mt = 0; mt < 2; ++mt)
#pragma unroll
        for (int nt = 0; nt < 8; ++nt)
            acc1[mt][nt] = (f32x4){0.f, 0.f, 0.f, 0.f};

#pragma unroll
    for (int ks = 0; ks < 2; ++ks) {
        const int kb = ks * 32 + q * 8;
#pragma unroll
        for (int nt = 0; nt < 8; ++nt) {
            const int m = nt * 16 + c;
            FragU bb;
            if (kb < SB) {                       // embedding slice (B[k][n=row])
                int j = kb >> 4, off = kb & 15;
                bb.u = *(const uint4*)&ebuf[seqb[m + j] * 16 + off];
            } else if (TYPE != 2 && kb == SB) {  // [geom, 1.0(bias), 0...]
                bb.u = make_uint4(0u, 0u, 0u, 0u);
                bb.s[0] = f2bf(geomb[m]);
                bb.s[1] = 0x3F80;
            } else {
                bb.u = make_uint4(0u, 0u, 0u, 0u);
            }
            acc1[0][nt] = __builtin_amdgcn_mfma_f32_16x16x32_bf16(A1[0][ks].v, bb.v, acc1[0][nt], 0, 0, 0);
            acc1[1][nt] = __builtin_amdgcn_mfma_f32_16x16x32_bf16(A1[1][ks].v, bb.v, acc1[1][nt], 0, 0, 0);
        }
    }

    // ---- H1 = relu(.) -> H1s, packed 8B writes (reg dim = hid = contiguous) ----
#pragma unroll
    for (int mt = 0; mt < 2; ++mt)
#pragma unroll
        for (int nt = 0; nt < 8; ++nt) {
            const int m = nt * 16 + c;
            float v0 = acc1[mt][nt][0], v1 = acc1[mt][nt][1];
            float v2 = acc1[mt][nt][2], v3 = acc1[mt][nt][3];
            if (TYPE == 2) {
                float gm0 = geomb[m], gm1 = geomb[128 + m];
                v0 += gm0 * g0v[mt * 4 + 0] + gm1 * g1v[mt * 4 + 0] + b1v[mt * 4 + 0];
                v1 += gm0 * g0v[mt * 4 + 1] + gm1 * g1v[mt * 4 + 1] + b1v[mt * 4 + 1];
                v2 += gm0 * g0v[mt * 4 + 2] + gm1 * g1v[mt * 4 + 2] + b1v[mt * 4 + 2];
                v3 += gm0 * g0v[mt * 4 + 3] + gm1 * g1v[mt * 4 + 3] + b1v[mt * 4 + 3];
            }
            v0 = fmaxf(v0, 0.f); v1 = fmaxf(v1, 0.f);
            v2 = fmaxf(v2, 0.f); v3 = fmaxf(v3, 0.f);
            uint2 pk;
            pk.x = pkbf(v0, v1);
            pk.y = pkbf(v2, v3);
            *(uint2*)&H1s[m * SHs + wv * 32 + mt * 16 + q * 4] = pk;
        }
    __syncthreads();

    // ---- GEMM2: acc2[mt][nt] = D[row][col2], W2 frags from registers ----
    f32x4 acc2[8][2];
#pragma unroll
    for (int mt = 0; mt < 8; ++mt)
#pragma unroll
        for (int nt = 0; nt < 2; ++nt)
            acc2[mt][nt] = (f32x4){0.f, 0.f, 0.f, 0.f};

#pragma unroll
    for (int ks = 0; ks < 4; ++ks)
#pragma unroll
        for (int mt = 0; mt < 8; ++mt) {
            bf16x8 aa = *(const bf16x8*)&H1s[(mt * 16 + c) * SHs + ks * 32 + q * 8];
            acc2[mt][0] = __builtin_amdgcn_mfma_f32_16x16x32_bf16(aa, B2[0][ks].v, acc2[mt][0], 0, 0, 0);
            acc2[mt][1] = __builtin_amdgcn_mfma_f32_16x16x32_bf16(aa, B2[1][ks].v, acc2[mt][1], 0, 0, 0);
        }

    // ---- epilogue: relu(h2 + b2) . w3 over this wave's col2 chunk ----
    float p = 0.0f;
#pragma unroll
    for (int mt = 0; mt < 8; ++mt)
#pragma unroll
        for (int rg = 0; rg < 4; ++rg) {
            int m = mt * 16 + q * 4 + rg;
            if (i0 + m < ROWSB) {
                p += fmaxf(acc2[mt][0][rg] + b2v[0], 0.f) * w3v[0];
                p += fmaxf(acc2[mt][1][rg] + b2v[1], 0.f) * w3v[1];
            }
        }
#pragma unroll
    for (int off = 32; off > 0; off >>= 1)
        p += __shfl_down(p, off);
    if (lane == 0) part[wv] = p;
    __syncthreads();
    if (tid == 0) {
        int vc = min(ROWSB - i0, 128);
        atomicAdd(&out[b], part[0] + part[1] + part[2] + part[3] + b3[0] * (float)vc);
    }
}

__global__ __launch_bounds__(256, 3)
void energy_kernel(const float* __restrict__ R, const int* __restrict__ seq,
                   const float* __restrict__ emb, const char* __restrict__ ws,
                   const float* W1_2, const float* b1_2,
                   const float* b2_0, const float* b2_1, const float* b2_2,
                   const float* w3_0, const float* w3_1, const float* w3_2,
                   const float* b3_0, const float* b3_1, const float* b3_2,
                   float* out)
{
    if (blockIdx.z == 0)
        body<0>(R, seq, emb, ws, nullptr, nullptr, b2_0, w3_0, b3_0, out);
    else if (blockIdx.z == 1)
        body<1>(R, seq, emb, ws, nullptr, nullptr, b2_1, w3_1, b3_1, out);
    else
        body<2>(R, seq, emb, ws, W1_2, b1_2, b2_2, w3_2, b3_2, out);
}

extern "C" void kernel_launch(void* const* d_in, const int* in_sizes, int n_in,
                              void* d_out, int out_size, void* d_ws, size_t ws_size,
                              hipStream_t stream) {
    const float* R   = (const float*)d_in[0];
    const int*   seq = (const int*)d_in[1];
    const float* emb = (const float*)d_in[2];
    float* out = (float*)d_out;
    char*  ws  = (char*)d_ws;

    prep_kernel<<<dim3(64), dim3(256), 0, stream>>>(
        (const float*)d_in[3],  (const float*)d_in[4],   // fl_W1, fl_b1
        (const float*)d_in[9],  (const float*)d_in[10],  // ft_W1, ft_b1
        (const float*)d_in[15],                          // fp_W1
        (const float*)d_in[5],  (const float*)d_in[11], (const float*)d_in[17],
        ws, out);

    dim3 grid(16, 128, 3), block(256);
    energy_kernel<<<grid, block, 38688, stream>>>(
        R, seq, emb, ws,
        (const float*)d_in[15], (const float*)d_in[16],
        (const float*)d_in[6],  (const float*)d_in[12], (const float*)d_in[18],
        (const float*)d_in[7],  (const float*)d_in[13], (const float*)d_in[19],
        (const float*)d_in[8],  (const float*)d_in[14], (const float*)d_in[20],
        out);
}